// Round 10
// baseline (217.784 us; speedup 1.0000x reference)
//
#include <hip/hip_runtime.h>

typedef __bf16 bf16;
typedef __bf16 bf16x8 __attribute__((ext_vector_type(8)));
typedef __bf16 bf16x4 __attribute__((ext_vector_type(4)));
typedef float  f32x4  __attribute__((ext_vector_type(4)));
typedef unsigned int u32;
typedef unsigned int u32x2 __attribute__((ext_vector_type(2)));
typedef unsigned int u32x4 __attribute__((ext_vector_type(4)));
typedef unsigned short u16;

#define MFMA16(a, b, c) __builtin_amdgcn_mfma_f32_16x16x32_bf16((a), (b), (c), 0, 0, 0)
#define L2E 1.4426950408889634f

// B=1, S=128, R=256, C=256, H=8, Ca=32.  M = S*R = 32768, K = 256.
// Workspace layouts (h-major, round-10):
//   QG:  [16][32768][32] bf16 — slices 0-7 = Q*norm (h), 8-15 = G*log2e (h)
//   KV:  [8][32768][64] bf16 — per h: cols 0-31 = K, 32-63 = V

// ---- async global->LDS, 16 B per lane ----
typedef __attribute__((address_space(3))) u32 lds_u32;
typedef const __attribute__((address_space(1))) u32 glob_u32;
__device__ __forceinline__ void gll16(const void* g, void* l) {
    __builtin_amdgcn_global_load_lds((glob_u32*)g, (lds_u32*)l, 16, 0, 0);
}

__device__ __forceinline__ u32 pk2(float lo, float hi) {
    u16 a = __builtin_bit_cast(u16, (bf16)lo);
    u16 b = __builtin_bit_cast(u16, (bf16)hi);
    return ((u32)b << 16) | (u32)a;
}

__device__ __forceinline__ bf16x8 cvt8(float4 a, float4 b) {
    bf16x8 t;
    t[0]=(bf16)a.x; t[1]=(bf16)a.y; t[2]=(bf16)a.z; t[3]=(bf16)a.w;
    t[4]=(bf16)b.x; t[5]=(bf16)b.y; t[6]=(bf16)b.z; t[7]=(bf16)b.w;
    return t;
}

__device__ __forceinline__ float fexp2(float x) {
#if __has_builtin(__builtin_amdgcn_exp2f)
    return __builtin_amdgcn_exp2f(x);
#else
    return exp2f(x);
#endif
}
__device__ __forceinline__ float frcp(float x) {
#if __has_builtin(__builtin_amdgcn_rcpf)
    return __builtin_amdgcn_rcpf(x);
#else
    return 1.0f / x;
#endif
}

// ================= prep: ONLY Wqg/Wkv (proj's B inputs) ========================
// biasT/Wo/b_gL moved into proj_kernel's extra blocks (only read by attn/outproj
// which launch after proj) — hides their cost under proj + drops one launch gap.
__global__ __launch_bounds__(256) void prep_kernel(
    const float* __restrict__ w_q, const float* __restrict__ w_k,
    const float* __restrict__ w_v, const float* __restrict__ w_g,
    bf16* __restrict__ Wqg, bf16* __restrict__ Wkv)
{
    const float norm = 0.17677669529663687f * L2E;   // 1/sqrt(32)*log2e (base-2 softmax)
    const int gid = blockIdx.x * 256 + threadIdx.x;
    const int gsz = gridDim.x * 256;

    for (int u = gid; u < 131072; u += gsz) {        // Wqg[n][k]
        int n = u >> 8, k = u & 255;
        float v = (n < 256) ? w_q[k * 256 + n] * norm : w_g[k * 256 + (n - 256)] * L2E;
        Wqg[u] = (bf16)v;
    }
    for (int u = gid; u < 131072; u += gsz) {        // Wkv[n][k]
        int n = u >> 8, k = u & 255;
        float v = (n < 256) ? w_k[k * 256 + n] : w_v[k * 256 + (n - 256)];
        Wkv[u] = (bf16)v;
    }
}

// ================= proj GEMM core (round-6 dbuf structure, +As stride-40 pad) ==
// 128x128 tile, BK=32, dbuf via 4 distinct __shared__ objects + unrolled steps
// (round-5 lesson: runtime LDS base defeats alias analysis).  Round-7 lesson:
// keep gll16 burst staging for B.  Round-10: As padded to 40 elems/row (A is
// reg-staged, padding legal) — stride-64B rows were an 8-way bank conflict on
// aF ds_reads; 80B rows -> 2-way = free (m136).  B (gll16, linear) unchanged.
// C-write goes to h-major slices (see layout comment at top).
__device__ __forceinline__ void proj_core(
    const float* __restrict__ A32, const bf16* __restrict__ Bw,
    bf16* __restrict__ Cb, int m0, int n0, bool kvmode)
{
    __shared__ __align__(16) bf16 As0[128 * 40], Bs0[128 * 32];
    __shared__ __align__(16) bf16 As1[128 * 40], Bs1[128 * 32];

    const int tid  = threadIdx.x;
    const int lane = tid & 63, wave = tid >> 6;
    const int quad = lane >> 4, lc = lane & 15;
    const int wr = wave >> 1, wc = wave & 1;

    const int r0 = tid >> 2, p0 = tid & 3;
    const size_t offA0 = (size_t)(m0 + r0) * 256 + p0 * 8;
    const size_t offA1 = (size_t)(m0 + 64 + r0) * 256 + p0 * 8;
    const bf16* gB0 = Bw + (size_t)(n0 + r0) * 256 + p0 * 8;
    const bf16* gB1 = Bw + (size_t)(n0 + 64 + r0) * 256 + p0 * 8;
    const int aw0 = r0 * 40 + p0 * 8;              // padded A LDS offsets
    const int aw1 = (r0 + 64) * 40 + p0 * 8;

    f32x4 acc[4][4];
    #pragma unroll
    for (int i = 0; i < 4; ++i)
        #pragma unroll
        for (int j = 0; j < 4; ++j) acc[i][j] = f32x4{0.f, 0.f, 0.f, 0.f};

    {
        float4 x0 = *(const float4*)(A32 + offA0);
        float4 x1 = *(const float4*)(A32 + offA0 + 4);
        float4 y0 = *(const float4*)(A32 + offA1);
        float4 y1 = *(const float4*)(A32 + offA1 + 4);
        *(bf16x8*)(As0 + aw0) = cvt8(x0, x1);
        *(bf16x8*)(As0 + aw1) = cvt8(y0, y1);
        gll16(gB0, Bs0 + tid * 8);
        gll16(gB1, Bs0 + (tid + 256) * 8);
    }
    __syncthreads();

    auto step = [&](const bf16* Ac, const bf16* Bc, bf16* An, bf16* Bn,
                    int kn, bool pf) {
        float4 x0, x1, y0, y1;
        if (pf) {
            x0 = *(const float4*)(A32 + offA0 + kn);
            x1 = *(const float4*)(A32 + offA0 + kn + 4);
            y0 = *(const float4*)(A32 + offA1 + kn);
            y1 = *(const float4*)(A32 + offA1 + kn + 4);
            gll16(gB0 + kn, Bn + tid * 8);
            gll16(gB1 + kn, Bn + (tid + 256) * 8);
        }
        __builtin_amdgcn_sched_barrier(0);  // staging stays above, compute below

        bf16x8 aF[4], bF[4];
        #pragma unroll
        for (int mt = 0; mt < 4; ++mt)
            aF[mt] = *(const bf16x8*)(Ac + (wr * 64 + mt * 16 + lc) * 40 + quad * 8);
        #pragma unroll
        for (int nt = 0; nt < 4; ++nt)
            bF[nt] = *(const bf16x8*)(Bc + (wc * 64 + nt * 16 + lc) * 32 + quad * 8);
        #pragma unroll
        for (int mt = 0; mt < 4; ++mt)
            #pragma unroll
            for (int nt = 0; nt < 4; ++nt)
                acc[mt][nt] = MFMA16(aF[mt], bF[nt], acc[mt][nt]);

        if (pf) {
            *(bf16x8*)(An + aw0) = cvt8(x0, x1);
            *(bf16x8*)(An + aw1) = cvt8(y0, y1);
        }
        __syncthreads();
    };

    step(As0, Bs0, As1, Bs1,  32, true);
    step(As1, Bs1, As0, Bs0,  64, true);
    step(As0, Bs0, As1, Bs1,  96, true);
    step(As1, Bs1, As0, Bs0, 128, true);
    step(As0, Bs0, As1, Bs1, 160, true);
    step(As1, Bs1, As0, Bs0, 192, true);
    step(As0, Bs0, As1, Bs1, 224, true);
    step(As1, Bs1, As0, Bs0,   0, false);

    // C-write into h-major slices.  colbase is 16-aligned; slice = colbase>>5
    // is constant per (nt); within-slice col = (colbase&16) + lc.
    #pragma unroll
    for (int mt = 0; mt < 4; ++mt) {
        #pragma unroll
        for (int nt = 0; nt < 4; ++nt) {
            const int row = m0 + wr * 64 + mt * 16 + quad * 4;
            const int colbase = n0 + wc * 64 + nt * 16;
            const int slice = colbase >> 5;
            const int cin = (colbase & 16) + lc;
            if (!kvmode) {
                // QG: [16][M][32]  addr = (slice<<20) + row*32 + cin
                bf16* dst = Cb + ((size_t)slice << 20) + ((size_t)row << 5) + cin;
                #pragma unroll
                for (int rr = 0; rr < 4; ++rr)
                    dst[rr * 32] = (bf16)acc[mt][nt][rr];
            } else {
                // KV: [8][M][64]  K at +0, V at +32
                const int hh = slice & 7, vofs = (slice >> 3) * 32;
                bf16* dst = Cb + ((size_t)hh << 21) + ((size_t)row << 6) + vofs + cin;
                #pragma unroll
                for (int rr = 0; rr < 4; ++rr)
                    dst[rr * 64] = (bf16)acc[mt][nt][rr];
            }
        }
    }
}

// XCD write/read alignment (round-9, kept): attn reads (s,h) from XCD s%8; map
// the m-strip so the writer's XCD = (strip>>1)%8.  Blocks >= 2048: prep part 2
// (biasT/Wo/b_gL — consumed only by later kernels; overlaps proj's tail).
__global__ __launch_bounds__(256) void proj_kernel(
    const float* __restrict__ qf, const float* __restrict__ kvf,
    const bf16* __restrict__ Wqg, const bf16* __restrict__ Wkv,
    bf16* __restrict__ QG, bf16* __restrict__ KV,
    const float* __restrict__ bias, const float* __restrict__ w_o,
    const float* __restrict__ b_g,
    float* __restrict__ biasT, bf16* __restrict__ Wo, float* __restrict__ b_gL)
{
    int bid = blockIdx.x;
    if (bid >= 2048) {
        const int gid = (bid - 2048) * 256 + threadIdx.x;
        const int gsz = 320 * 256;
        for (int u = gid; u < 524288; u += gsz) {    // biasT[h][q][k] * log2e
            int h = u >> 16, qq = (u >> 8) & 255, kk = u & 255;
            biasT[u] = bias[(((qq << 8) + kk) << 3) + h] * L2E;
        }
        for (int u = gid; u < 65536; u += gsz) {     // Wo[n][k]
            int n = u >> 8, k = u & 255;
            Wo[u] = (bf16)w_o[k * 256 + n];
        }
        if (gid < 256) b_gL[gid] = b_g[gid] * L2E;
        return;
    }
    bool sel = bid >= 1024;
    int b = bid & 1023;
    int strip = ((b >> 3) & 1) | ((b & 7) << 1) | (((b >> 4) & 15) << 4);
    int m0 = strip * 128, n0 = (b >> 8) * 128;
    proj_core(sel ? kvf : qf, sel ? Wkv : Wqg, sel ? KV : QG, m0, n0, sel);
}

// ============ outproj: out[M][256] = OG[M][256] @ Wo[256][256]^T + b_o =========
// 64x128 tile, grid 1024 (round-8: 512 blocks was grid-limited).  Reader strip
// mapped so XCD = s%8 -> OG (2.1 MB/XCD) is read from the writer XCD's L2.
__global__ __launch_bounds__(256) void outproj_kernel(
    const bf16* __restrict__ OG, const bf16* __restrict__ Wo,
    const float* __restrict__ bo, float* __restrict__ out)
{
    __shared__ __align__(16) bf16 As0[64 * 32], Bs0[128 * 32];
    __shared__ __align__(16) bf16 As1[64 * 32], Bs1[128 * 32];

    const int bid = blockIdx.x;
    const int x = bid & 7;
    const int strip = ((bid >> 3) & 3) | (x << 2) | (((bid >> 5) & 15) << 5);
    const int m0 = strip * 64, n0 = (bid >> 9) * 128;

    const int tid  = threadIdx.x;
    const int lane = tid & 63, wave = tid >> 6;
    const int quad = lane >> 4, lc = lane & 15;
    const int wr = wave >> 1, wc = wave & 1;   // wave tile: 32 x 64

    const int r0 = tid >> 2, p0 = tid & 3;
    const bf16* gA  = OG + (size_t)(m0 + r0) * 256 + p0 * 8;
    const bf16* gB0 = Wo + (size_t)(n0 + r0) * 256 + p0 * 8;
    const bf16* gB1 = Wo + (size_t)(n0 + 64 + r0) * 256 + p0 * 8;

    f32x4 acc[2][4];
    #pragma unroll
    for (int i = 0; i < 2; ++i)
        #pragma unroll
        for (int j = 0; j < 4; ++j) acc[i][j] = f32x4{0.f, 0.f, 0.f, 0.f};

    gll16(gA,  As0 + tid * 8);
    gll16(gB0, Bs0 + tid * 8);
    gll16(gB1, Bs0 + (tid + 256) * 8);
    __syncthreads();

    auto step = [&](const bf16* Ac, const bf16* Bc, bf16* An, bf16* Bn,
                    int kn, bool pf) {
        if (pf) {
            gll16(gA + kn,  An + tid * 8);
            gll16(gB0 + kn, Bn + tid * 8);
            gll16(gB1 + kn, Bn + (tid + 256) * 8);
        }
        __builtin_amdgcn_sched_barrier(0);

        bf16x8 aF[2], bF[4];
        #pragma unroll
        for (int mt = 0; mt < 2; ++mt)
            aF[mt] = *(const bf16x8*)(Ac + (wr * 32 + mt * 16 + lc) * 32 + quad * 8);
        #pragma unroll
        for (int nt = 0; nt < 4; ++nt)
            bF[nt] = *(const bf16x8*)(Bc + (wc * 64 + nt * 16 + lc) * 32 + quad * 8);
        #pragma unroll
        for (int mt = 0; mt < 2; ++mt)
            #pragma unroll
            for (int nt = 0; nt < 4; ++nt)
                acc[mt][nt] = MFMA16(aF[mt], bF[nt], acc[mt][nt]);
        __syncthreads();
    };

    step(As0, Bs0, As1, Bs1,  32, true);
    step(As1, Bs1, As0, Bs0,  64, true);
    step(As0, Bs0, As1, Bs1,  96, true);
    step(As1, Bs1, As0, Bs0, 128, true);
    step(As0, Bs0, As1, Bs1, 160, true);
    step(As1, Bs1, As0, Bs0, 192, true);
    step(As0, Bs0, As1, Bs1, 224, true);
    step(As1, Bs1, As0, Bs0,   0, false);

    #pragma unroll
    for (int mt = 0; mt < 2; ++mt) {
        #pragma unroll
        for (int nt = 0; nt < 4; ++nt) {
            const int row = m0 + wr * 32 + mt * 16 + quad * 4;
            const int col = n0 + wc * 64 + nt * 16 + lc;
            const float bb = bo[col];
            #pragma unroll
            for (int rr = 0; rr < 4; ++rr)
                out[(size_t)(row + rr) * 256 + col] = acc[mt][nt][rr] + bb;
        }
    }
}

// ================= attention per (s,h) — h-major inputs (round-10) =============
// Swapped QK^T; in-register base-2 softmax; P -> PV B-operand via permlane
// swaps; two 8-kt halves cap VGPR at 64.  h-major layout makes KV staging 128 B
// contiguous per thread (wave = 8 KB streak) and shrinks qf/gate windows 16x.
#define A_OFF_MASK 0
#define A_OFF_K    1024
#define A_OFF_VT   21504
#define A_LDS_TOT  (21504 + 32 * 264 * 2)   // 38400 B -> 4 blocks/CU

__global__ __launch_bounds__(256) void attn_kernel(
    const bf16* __restrict__ QG, const bf16* __restrict__ KV,
    const float* __restrict__ biasT, const float* __restrict__ bias_mask,
    const float* __restrict__ b_gL, bf16* __restrict__ OG)
{
    __shared__ __align__(16) char smem[A_LDS_TOT];
    float* maskadd = (float*)(smem + A_OFF_MASK);
    bf16*  Ks      = (bf16*)(smem + A_OFF_K);
    bf16*  Vt      = (bf16*)(smem + A_OFF_VT);

    const int tid  = threadIdx.x;
    const int wave = tid >> 6, lane = tid & 63;
    const int quad = lane >> 4, lc = lane & 15;
    const int h = blockIdx.x >> 7;       // all h of same s -> same XCD (bid%8 = s%8)
    const int s = blockIdx.x & 127;

    const bf16* Qh  = QG + ((size_t)h << 20);          // [M][32] Q slice
    const bf16* Gh  = QG + ((size_t)(8 + h) << 20);    // [M][32] G slice
    const bf16* KVh = KV + ((size_t)h << 21);          // [M][64] K|V slice

    maskadd[tid] = (bias_mask[s * 256 + tid] - 1.0f) * (1e9f * L2E);
    {
        const bf16* kvrow = KVh + (size_t)(s * 256 + tid) * 64;  // 128 B contiguous
        #pragma unroll
        for (int j = 0; j < 4; ++j)
            *(bf16x8*)(Ks + tid * 40 + j * 8) = *(const bf16x8*)(kvrow + j * 8);
        bf16x8 vx[4];
        #pragma unroll
        for (int j = 0; j < 4; ++j) vx[j] = *(const bf16x8*)(kvrow + 32 + j * 8);
        #pragma unroll
        for (int d = 0; d < 32; ++d)
            Vt[d * 264 + tid] = vx[d >> 3][d & 7];
    }
    __syncthreads();

    const f32x4 bg0 = *(const f32x4*)(b_gL + h * 32 + quad * 4);
    const f32x4 bg1 = *(const f32x4*)(b_gL + h * 32 + 16 + quad * 4);

    #pragma unroll 1
    for (int p = 0; p < 4; ++p) {
        const int q0 = (wave * 4 + p) * 16;

        bf16x8 qf = *(const bf16x8*)(Qh + (size_t)(s * 256 + q0 + lc) * 32 + quad * 8);

        const float* bT = biasT + (((size_t)h * 256 + q0 + lc) << 8) + quad * 4;
        u32x2 cw[16];
        float sum = 0.f;
        #pragma unroll
        for (int half = 0; half < 2; ++half) {
            f32x4 sc[8];
            #pragma unroll
            for (int k8 = 0; k8 < 8; ++k8) {
                const int kt = half * 8 + k8;
                bf16x8 kf = *(const bf16x8*)(Ks + (kt * 16 + lc) * 40 + quad * 8);
                f32x4 z = {0.f, 0.f, 0.f, 0.f};
                sc[k8] = MFMA16(kf, qf, z);
            }
            #pragma unroll
            for (int k8 = 0; k8 < 8; ++k8) {
                const int kt = half * 8 + k8;
                f32x4 bv = *(const f32x4*)(bT + kt * 16);
                f32x4 mv = *(const f32x4*)(maskadd + kt * 16 + quad * 4);
                f32x4 t = sc[k8] + bv + mv;
                float e0 = fexp2(t[0]);
                float e1 = fexp2(t[1]);
                float e2 = fexp2(t[2]);
                float e3 = fexp2(t[3]);
                sum += (e0 + e1) + (e2 + e3);
                cw[kt] = u32x2{pk2(e0, e1), pk2(e2, e3)};
            }
            __builtin_amdgcn_sched_barrier(0x6);  // VALU/SALU may cross; MFMA/DS pinned
        }

        const bf16* gp = Gh + (size_t)(s * 256 + q0 + lc) * 32 + quad * 4;
        bf16x4 gv0 = *(const bf16x4*)(gp);
        bf16x4 gv1 = *(const bf16x4*)(gp + 16);

        f32x4 o0 = {0.f, 0.f, 0.f, 0.f}, o1 = {0.f, 0.f, 0.f, 0.f};
        #pragma unroll
        for (int ks = 0; ks < 8; ++ks) {
            u32 c0 = cw[2 * ks].x,     c1 = cw[2 * ks].y;
            u32 c2 = cw[2 * ks + 1].x, c3 = cw[2 * ks + 1].y;
            u32x2 s02 = __builtin_amdgcn_permlane32_swap(c0, c2, false, false);
            u32x2 s13 = __builtin_amdgcn_permlane32_swap(c1, c3, false, false);
            u32x2 e02 = __builtin_amdgcn_permlane16_swap(s02.x, s02.y, false, false);
            u32x2 e13 = __builtin_amdgcn_permlane16_swap(s13.x, s13.y, false, false);
            u32x4 pw = {e02.x, e13.x, e02.y, e13.y};
            bf16x8 pf = __builtin_bit_cast(bf16x8, pw);
            bf16x8 v0 = *(const bf16x8*)(Vt + lc * 264 + ks * 32 + quad * 8);
            bf16x8 v1 = *(const bf16x8*)(Vt + (16 + lc) * 264 + ks * 32 + quad * 8);
            o0 = MFMA16(v0, pf, o0);
            o1 = MFMA16(v1, pf, o1);
        }

        sum += __shfl_xor(sum, 16, 64);
        sum += __shfl_xor(sum, 32, 64);
        const float inv = frcp(sum);

        bf16* op = OG + (size_t)(s * 256 + q0 + lc) * 256 + h * 32 + quad * 4;
        #pragma unroll
        for (int nt = 0; nt < 2; ++nt) {
            f32x4 ov = nt ? o1 : o0;
            f32x4 bg = nt ? bg1 : bg0;
            bf16x4 gv = nt ? gv1 : gv0;
            bf16x4 ob;
            #pragma unroll
            for (int rr = 0; rr < 4; ++rr) {
                float e = fexp2(-((float)gv[rr] + bg[rr]));
                float g = frcp(1.0f + e);
                ob[rr] = (bf16)(ov[rr] * (inv * g));
            }
            *(bf16x4*)(op + nt * 16) = ob;
        }
    }
}

// ================= launch =================
extern "C" void kernel_launch(void* const* d_in, const int* in_sizes, int n_in,
                              void* d_out, int out_size, void* d_ws, size_t ws_size,
                              hipStream_t stream)
{
    (void)in_sizes; (void)n_in; (void)out_size; (void)ws_size;
    const float* q    = (const float*)d_in[0];
    const float* kv   = (const float*)d_in[1];
    const float* bias = (const float*)d_in[2];
    const float* mask = (const float*)d_in[3];
    const float* w_q  = (const float*)d_in[4];
    const float* w_k  = (const float*)d_in[5];
    const float* w_v  = (const float*)d_in[6];
    const float* w_g  = (const float*)d_in[7];
    const float* b_g  = (const float*)d_in[8];
    const float* w_o  = (const float*)d_in[9];
    const float* b_o  = (const float*)d_in[10];
    float* out = (float*)d_out;

    char* ws = (char*)d_ws;
    bf16*  OG    = (bf16*)(ws + 0);           // 16.78 MB  [M][256]
    bf16*  QG    = (bf16*)(ws + 33554432);    // 33.55 MB  [16][M][32] h-major
    bf16*  KV    = (bf16*)(ws + 67108864);    // 33.55 MB  [8][M][64]  h-major
    float* biasT = (float*)(ws + 100663296);  //  2.10 MB  [h][q][k] * log2e
    bf16*  Wqg   = (bf16*)(ws + 102760448);   //  0.26 MB
    bf16*  Wkv   = (bf16*)(ws + 103022592);   //  0.26 MB
    bf16*  Wo    = (bf16*)(ws + 103284736);   //  0.13 MB
    float* b_gL  = (float*)(ws + 103415808);  //  1 KB

    prep_kernel<<<64, 256, 0, stream>>>(w_q, w_k, w_v, w_g, Wqg, Wkv);
    proj_kernel<<<2368, 256, 0, stream>>>(q, kv, Wqg, Wkv, QG, KV,
                                          bias, w_o, b_g, biasT, Wo, b_gL);
    attn_kernel<<<1024, 256, 0, stream>>>(QG, KV, biasT, mask, b_gL, OG);
    outproj_kernel<<<1024, 256, 0, stream>>>(OG, Wo, b_o, out);
}

// Round 11
// 217.553 us; speedup vs baseline: 1.0011x; 1.0011x over previous
//
#include <hip/hip_runtime.h>

typedef __bf16 bf16;
typedef __bf16 bf16x8 __attribute__((ext_vector_type(8)));
typedef __bf16 bf16x4 __attribute__((ext_vector_type(4)));
typedef float  f32x4  __attribute__((ext_vector_type(4)));
typedef unsigned int u32;
typedef unsigned int u32x2 __attribute__((ext_vector_type(2)));
typedef unsigned int u32x4 __attribute__((ext_vector_type(4)));
typedef unsigned short u16;

#define MFMA16(a, b, c) __builtin_amdgcn_mfma_f32_16x16x32_bf16((a), (b), (c), 0, 0, 0)
#define L2E 1.4426950408889634f

// B=1, S=128, R=256, C=256, H=8, Ca=32.  M = S*R = 32768, K = 256.

// ---- async global->LDS, 16 B per lane ----
typedef __attribute__((address_space(3))) u32 lds_u32;
typedef const __attribute__((address_space(1))) u32 glob_u32;
__device__ __forceinline__ void gll16(const void* g, void* l) {
    __builtin_amdgcn_global_load_lds((glob_u32*)g, (lds_u32*)l, 16, 0, 0);
}

__device__ __forceinline__ u32 pk2(float lo, float hi) {
    u16 a = __builtin_bit_cast(u16, (bf16)lo);
    u16 b = __builtin_bit_cast(u16, (bf16)hi);
    return ((u32)b << 16) | (u32)a;
}

__device__ __forceinline__ bf16x8 cvt8(float4 a, float4 b) {
    bf16x8 t;
    t[0]=(bf16)a.x; t[1]=(bf16)a.y; t[2]=(bf16)a.z; t[3]=(bf16)a.w;
    t[4]=(bf16)b.x; t[5]=(bf16)b.y; t[6]=(bf16)b.z; t[7]=(bf16)b.w;
    return t;
}

__device__ __forceinline__ float fexp2(float x) {
#if __has_builtin(__builtin_amdgcn_exp2f)
    return __builtin_amdgcn_exp2f(x);
#else
    return exp2f(x);
#endif
}
__device__ __forceinline__ float frcp(float x) {
#if __has_builtin(__builtin_amdgcn_rcpf)
    return __builtin_amdgcn_rcpf(x);
#else
    return 1.0f / x;
#endif
}

// ================= prep (round-9 version: separate, proven) ====================
__global__ __launch_bounds__(256) void prep_kernel(
    const float* __restrict__ bias,
    const float* __restrict__ w_q, const float* __restrict__ w_k,
    const float* __restrict__ w_v, const float* __restrict__ w_g,
    const float* __restrict__ w_o, const float* __restrict__ b_g,
    float* __restrict__ biasT,
    bf16* __restrict__ Wqg, bf16* __restrict__ Wkv, bf16* __restrict__ Wo,
    float* __restrict__ b_gL)
{
    const float norm = 0.17677669529663687f * L2E;   // 1/sqrt(32)*log2e (base-2 softmax)
    const int gid = blockIdx.x * 256 + threadIdx.x;
    const int gsz = gridDim.x * 256;

    for (int u = gid; u < 524288; u += gsz) {        // biasT[h][q][k] * log2e
        int h = u >> 16, qq = (u >> 8) & 255, kk = u & 255;
        biasT[u] = bias[(((qq << 8) + kk) << 3) + h] * L2E;
    }
    for (int u = gid; u < 131072; u += gsz) {        // Wqg[n][k]
        int n = u >> 8, k = u & 255;
        float v = (n < 256) ? w_q[k * 256 + n] * norm : w_g[k * 256 + (n - 256)] * L2E;
        Wqg[u] = (bf16)v;
    }
    for (int u = gid; u < 131072; u += gsz) {        // Wkv[n][k]
        int n = u >> 8, k = u & 255;
        float v = (n < 256) ? w_k[k * 256 + n] : w_v[k * 256 + (n - 256)];
        Wkv[u] = (bf16)v;
    }
    for (int u = gid; u < 65536; u += gsz) {         // Wo[n][k]
        int n = u >> 8, k = u & 255;
        Wo[u] = (bf16)w_o[k * 256 + n];
    }
    for (int u = gid; u < 256; u += gsz) b_gL[u] = b_g[u] * L2E;
}

// ================= proj GEMM: 64x128 tile (round-11 retile) ====================
// Round-9 proj (128x128, 32KB LDS) sat at 3.4x its memory floor with occupancy
// 34% and no saturated pipe — latency-starved.  outproj's 64x128 shape (24KB
// LDS -> 6 blocks/CU) runs at 1.9x floor with the same staging structure, so
// the resident-block count is the lever.  Per-step MFMA:staging ratio is
// unchanged (8:3 vs 16:6); only TLP grows.  dbuf via 4 distinct __shared__
// objects + unrolled steps (round-5 lesson); gll16 bursts for B (round-7
// lesson); A reg-staged f32->bf16 (fused convert); no As pad (round-10 lesson:
// pad helped reads but conflicted the staging writes, net worse).
__device__ __forceinline__ void proj_core(
    const float* __restrict__ A32, const bf16* __restrict__ Bw,
    bf16* __restrict__ Cb, int m0, int n0)
{
    __shared__ __align__(16) bf16 As0[64 * 32], Bs0[128 * 32];
    __shared__ __align__(16) bf16 As1[64 * 32], Bs1[128 * 32];

    const int tid  = threadIdx.x;
    const int lane = tid & 63, wave = tid >> 6;
    const int quad = lane >> 4, lc = lane & 15;
    const int wr = wave >> 1, wc = wave & 1;     // wave tile: 32 x 64

    const int r0 = tid >> 2, p0 = tid & 3;       // r0: 0..63
    const size_t offA = (size_t)(m0 + r0) * 256 + p0 * 8;
    const bf16* gB0 = Bw + (size_t)(n0 + r0) * 256 + p0 * 8;
    const bf16* gB1 = Bw + (size_t)(n0 + 64 + r0) * 256 + p0 * 8;

    f32x4 acc[2][4];
    #pragma unroll
    for (int i = 0; i < 2; ++i)
        #pragma unroll
        for (int j = 0; j < 4; ++j) acc[i][j] = f32x4{0.f, 0.f, 0.f, 0.f};

    {
        float4 x0 = *(const float4*)(A32 + offA);
        float4 x1 = *(const float4*)(A32 + offA + 4);
        *(bf16x8*)(As0 + tid * 8) = cvt8(x0, x1);
        gll16(gB0, Bs0 + tid * 8);
        gll16(gB1, Bs0 + (tid + 256) * 8);
    }
    __syncthreads();

    auto step = [&](const bf16* Ac, const bf16* Bc, bf16* An, bf16* Bn,
                    int kn, bool pf) {
        float4 x0, x1;
        if (pf) {
            x0 = *(const float4*)(A32 + offA + kn);
            x1 = *(const float4*)(A32 + offA + kn + 4);
            gll16(gB0 + kn, Bn + tid * 8);
            gll16(gB1 + kn, Bn + (tid + 256) * 8);
        }
        __builtin_amdgcn_sched_barrier(0);  // staging stays above, compute below

        bf16x8 aF[2], bF[4];
        #pragma unroll
        for (int mt = 0; mt < 2; ++mt)
            aF[mt] = *(const bf16x8*)(Ac + (wr * 32 + mt * 16 + lc) * 32 + quad * 8);
        #pragma unroll
        for (int nt = 0; nt < 4; ++nt)
            bF[nt] = *(const bf16x8*)(Bc + (wc * 64 + nt * 16 + lc) * 32 + quad * 8);
        #pragma unroll
        for (int mt = 0; mt < 2; ++mt)
            #pragma unroll
            for (int nt = 0; nt < 4; ++nt)
                acc[mt][nt] = MFMA16(aF[mt], bF[nt], acc[mt][nt]);

        if (pf) *(bf16x8*)(An + tid * 8) = cvt8(x0, x1);
        __syncthreads();
    };

    step(As0, Bs0, As1, Bs1,  32, true);
    step(As1, Bs1, As0, Bs0,  64, true);
    step(As0, Bs0, As1, Bs1,  96, true);
    step(As1, Bs1, As0, Bs0, 128, true);
    step(As0, Bs0, As1, Bs1, 160, true);
    step(As1, Bs1, As0, Bs0, 192, true);
    step(As0, Bs0, As1, Bs1, 224, true);
    step(As1, Bs1, As0, Bs0,   0, false);

    #pragma unroll
    for (int mt = 0; mt < 2; ++mt) {
        #pragma unroll
        for (int nt = 0; nt < 4; ++nt) {
            const int row = m0 + wr * 32 + mt * 16 + quad * 4;
            const int col = n0 + wc * 64 + nt * 16 + lc;
            #pragma unroll
            for (int rr = 0; rr < 4; ++rr)
                Cb[(size_t)(row + rr) * 512 + col] = (bf16)acc[mt][nt][rr];
        }
    }
}

// Grid 4096: bid>=2048 -> kv.  b9 = bid&511, n = (bid&2047)>>9.
// Strip remap (bijective, 9 bits): strip[1:0]=b9[4:3], strip[4:2]=b9[2:0],
// strip[8:5]=b9[8:5].  With 64-row strips, s = strip>>2, and XCD = bid%8 =
// b9[2:0] = strip[4:2] = s%8 -> writer XCD matches attn's reader (round-9 win,
// now exact).  The 4 strips of an s are <=24 dispatches apart (co-resident).
__global__ __launch_bounds__(256) void proj_kernel(
    const float* __restrict__ qf, const float* __restrict__ kvf,
    const bf16* __restrict__ Wqg, const bf16* __restrict__ Wkv,
    bf16* __restrict__ QG, bf16* __restrict__ KV)
{
    int bid = blockIdx.x;
    bool sel = bid >= 2048;
    int b = bid & 2047;
    int b9 = b & 511;
    int strip = ((b9 >> 3) & 3) | ((b9 & 7) << 2) | (((b9 >> 5) & 15) << 5);
    int m0 = strip * 64, n0 = (b >> 9) * 128;
    proj_core(sel ? kvf : qf, sel ? Wkv : Wqg, sel ? KV : QG, m0, n0);
}

// ============ outproj (round-9 version, unchanged: ~15us) ======================
__global__ __launch_bounds__(256) void outproj_kernel(
    const bf16* __restrict__ OG, const bf16* __restrict__ Wo,
    const float* __restrict__ bo, float* __restrict__ out)
{
    __shared__ __align__(16) bf16 As0[64 * 32], Bs0[128 * 32];
    __shared__ __align__(16) bf16 As1[64 * 32], Bs1[128 * 32];

    const int bid = blockIdx.x;
    const int x = bid & 7;
    const int strip = ((bid >> 3) & 3) | (x << 2) | (((bid >> 5) & 15) << 5);
    const int m0 = strip * 64, n0 = (bid >> 9) * 128;

    const int tid  = threadIdx.x;
    const int lane = tid & 63, wave = tid >> 6;
    const int quad = lane >> 4, lc = lane & 15;
    const int wr = wave >> 1, wc = wave & 1;   // wave tile: 32 x 64

    const int r0 = tid >> 2, p0 = tid & 3;
    const bf16* gA  = OG + (size_t)(m0 + r0) * 256 + p0 * 8;
    const bf16* gB0 = Wo + (size_t)(n0 + r0) * 256 + p0 * 8;
    const bf16* gB1 = Wo + (size_t)(n0 + 64 + r0) * 256 + p0 * 8;

    f32x4 acc[2][4];
    #pragma unroll
    for (int i = 0; i < 2; ++i)
        #pragma unroll
        for (int j = 0; j < 4; ++j) acc[i][j] = f32x4{0.f, 0.f, 0.f, 0.f};

    gll16(gA,  As0 + tid * 8);
    gll16(gB0, Bs0 + tid * 8);
    gll16(gB1, Bs0 + (tid + 256) * 8);
    __syncthreads();

    auto step = [&](const bf16* Ac, const bf16* Bc, bf16* An, bf16* Bn,
                    int kn, bool pf) {
        if (pf) {
            gll16(gA + kn,  An + tid * 8);
            gll16(gB0 + kn, Bn + tid * 8);
            gll16(gB1 + kn, Bn + (tid + 256) * 8);
        }
        __builtin_amdgcn_sched_barrier(0);

        bf16x8 aF[2], bF[4];
        #pragma unroll
        for (int mt = 0; mt < 2; ++mt)
            aF[mt] = *(const bf16x8*)(Ac + (wr * 32 + mt * 16 + lc) * 32 + quad * 8);
        #pragma unroll
        for (int nt = 0; nt < 4; ++nt)
            bF[nt] = *(const bf16x8*)(Bc + (wc * 64 + nt * 16 + lc) * 32 + quad * 8);
        #pragma unroll
        for (int mt = 0; mt < 2; ++mt)
            #pragma unroll
            for (int nt = 0; nt < 4; ++nt)
                acc[mt][nt] = MFMA16(aF[mt], bF[nt], acc[mt][nt]);
        __syncthreads();
    };

    step(As0, Bs0, As1, Bs1,  32, true);
    step(As1, Bs1, As0, Bs0,  64, true);
    step(As0, Bs0, As1, Bs1,  96, true);
    step(As1, Bs1, As0, Bs0, 128, true);
    step(As0, Bs0, As1, Bs1, 160, true);
    step(As1, Bs1, As0, Bs0, 192, true);
    step(As0, Bs0, As1, Bs1, 224, true);
    step(As1, Bs1, As0, Bs0,   0, false);

    #pragma unroll
    for (int mt = 0; mt < 2; ++mt) {
        #pragma unroll
        for (int nt = 0; nt < 4; ++nt) {
            const int row = m0 + wr * 32 + mt * 16 + quad * 4;
            const int col = n0 + wc * 64 + nt * 16 + lc;
            const float bb = bo[col];
            #pragma unroll
            for (int rr = 0; rr < 4; ++rr)
                out[(size_t)(row + rr) * 256 + col] = acc[mt][nt][rr] + bb;
        }
    }
}

// ================= attention per (s,h) — round-9 version (best: ~52us) =========
#define A_OFF_MASK 0
#define A_OFF_K    1024
#define A_OFF_VT   21504
#define A_LDS_TOT  (21504 + 32 * 264 * 2)   // 38400 B -> 4 blocks/CU

__global__ __launch_bounds__(256) void attn_kernel(
    const bf16* __restrict__ QG, const bf16* __restrict__ KV,
    const float* __restrict__ biasT, const float* __restrict__ bias_mask,
    const float* __restrict__ b_gL, bf16* __restrict__ OG)
{
    __shared__ __align__(16) char smem[A_LDS_TOT];
    float* maskadd = (float*)(smem + A_OFF_MASK);
    bf16*  Ks      = (bf16*)(smem + A_OFF_K);
    bf16*  Vt      = (bf16*)(smem + A_OFF_VT);

    const int tid  = threadIdx.x;
    const int wave = tid >> 6, lane = tid & 63;
    const int quad = lane >> 4, lc = lane & 15;
    const int h = blockIdx.x >> 7;       // all h of same s -> same XCD (bid%8 = s%8)
    const int s = blockIdx.x & 127;

    maskadd[tid] = (bias_mask[s * 256 + tid] - 1.0f) * (1e9f * L2E);
    {
        const bf16* kvrow = KV + (size_t)(s * 256 + tid) * 512 + h * 32;
        #pragma unroll
        for (int j = 0; j < 4; ++j)
            *(bf16x8*)(Ks + tid * 40 + j * 8) = *(const bf16x8*)(kvrow + j * 8);
        bf16x8 vx[4];
        #pragma unroll
        for (int j = 0; j < 4; ++j) vx[j] = *(const bf16x8*)(kvrow + 256 + j * 8);
        #pragma unroll
        for (int d = 0; d < 32; ++d)
            Vt[d * 264 + tid] = vx[d >> 3][d & 7];
    }
    __syncthreads();

    const f32x4 bg0 = *(const f32x4*)(b_gL + h * 32 + quad * 4);
    const f32x4 bg1 = *(const f32x4*)(b_gL + h * 32 + 16 + quad * 4);

    #pragma unroll 1
    for (int p = 0; p < 4; ++p) {
        const int q0 = (wave * 4 + p) * 16;

        bf16x8 qf = *(const bf16x8*)(QG + (size_t)(s * 256 + q0 + lc) * 512 + h * 32 + quad * 8);

        const float* bT = biasT + (((size_t)h * 256 + q0 + lc) << 8) + quad * 4;
        u32x2 cw[16];
        float sum = 0.f;
        #pragma unroll
        for (int half = 0; half < 2; ++half) {
            f32x4 sc[8];
            #pragma unroll
            for (int k8 = 0; k8 < 8; ++k8) {
                const int kt = half * 8 + k8;
                bf16x8 kf = *(const bf16x8*)(Ks + (kt * 16 + lc) * 40 + quad * 8);
                f32x4 z = {0.f, 0.f, 0.f, 0.f};
                sc[k8] = MFMA16(kf, qf, z);
            }
            #pragma unroll
            for (int k8 = 0; k8 < 8; ++k8) {
                const int kt = half * 8 + k8;
                f32x4 bv = *(const f32x4*)(bT + kt * 16);
                f32x4 mv = *(const f32x4*)(maskadd + kt * 16 + quad * 4);
                f32x4 t = sc[k8] + bv + mv;
                float e0 = fexp2(t[0]);
                float e1 = fexp2(t[1]);
                float e2 = fexp2(t[2]);
                float e3 = fexp2(t[3]);
                sum += (e0 + e1) + (e2 + e3);
                cw[kt] = u32x2{pk2(e0, e1), pk2(e2, e3)};
            }
            __builtin_amdgcn_sched_barrier(0x6);
        }

        const bf16* gp = QG + (size_t)(s * 256 + q0 + lc) * 512 + 256 + h * 32 + quad * 4;
        bf16x4 gv0 = *(const bf16x4*)(gp);
        bf16x4 gv1 = *(const bf16x4*)(gp + 16);

        f32x4 o0 = {0.f, 0.f, 0.f, 0.f}, o1 = {0.f, 0.f, 0.f, 0.f};
        #pragma unroll
        for (int ks = 0; ks < 8; ++ks) {
            u32 c0 = cw[2 * ks].x,     c1 = cw[2 * ks].y;
            u32 c2 = cw[2 * ks + 1].x, c3 = cw[2 * ks + 1].y;
            u32x2 s02 = __builtin_amdgcn_permlane32_swap(c0, c2, false, false);
            u32x2 s13 = __builtin_amdgcn_permlane32_swap(c1, c3, false, false);
            u32x2 e02 = __builtin_amdgcn_permlane16_swap(s02.x, s02.y, false, false);
            u32x2 e13 = __builtin_amdgcn_permlane16_swap(s13.x, s13.y, false, false);
            u32x4 pw = {e02.x, e13.x, e02.y, e13.y};
            bf16x8 pf = __builtin_bit_cast(bf16x8, pw);
            bf16x8 v0 = *(const bf16x8*)(Vt + lc * 264 + ks * 32 + quad * 8);
            bf16x8 v1 = *(const bf16x8*)(Vt + (16 + lc) * 264 + ks * 32 + quad * 8);
            o0 = MFMA16(v0, pf, o0);
            o1 = MFMA16(v1, pf, o1);
        }

        sum += __shfl_xor(sum, 16, 64);
        sum += __shfl_xor(sum, 32, 64);
        const float inv = frcp(sum);

        bf16* op = OG + (size_t)(s * 256 + q0 + lc) * 256 + h * 32 + quad * 4;
        #pragma unroll
        for (int nt = 0; nt < 2; ++nt) {
            f32x4 ov = nt ? o1 : o0;
            f32x4 bg = nt ? bg1 : bg0;
            bf16x4 gv = nt ? gv1 : gv0;
            bf16x4 ob;
            #pragma unroll
            for (int rr = 0; rr < 4; ++rr) {
                float e = fexp2(-((float)gv[rr] + bg[rr]));
                float g = frcp(1.0f + e);
                ob[rr] = (bf16)(ov[rr] * (inv * g));
            }
            *(bf16x4*)(op + nt * 16) = ob;
        }
    }
}

// ================= launch =================
extern "C" void kernel_launch(void* const* d_in, const int* in_sizes, int n_in,
                              void* d_out, int out_size, void* d_ws, size_t ws_size,
                              hipStream_t stream)
{
    (void)in_sizes; (void)n_in; (void)out_size; (void)ws_size;
    const float* q    = (const float*)d_in[0];
    const float* kv   = (const float*)d_in[1];
    const float* bias = (const float*)d_in[2];
    const float* mask = (const float*)d_in[3];
    const float* w_q  = (const float*)d_in[4];
    const float* w_k  = (const float*)d_in[5];
    const float* w_v  = (const float*)d_in[6];
    const float* w_g  = (const float*)d_in[7];
    const float* b_g  = (const float*)d_in[8];
    const float* w_o  = (const float*)d_in[9];
    const float* b_o  = (const float*)d_in[10];
    float* out = (float*)d_out;

    char* ws = (char*)d_ws;
    bf16*  OG    = (bf16*)(ws + 0);           // 16.78 MB  [M][256]
    bf16*  QG    = (bf16*)(ws + 33554432);    // 33.55 MB  [32768][512] = [Q*norm | G*l2e]
    bf16*  KV    = (bf16*)(ws + 67108864);    // 33.55 MB  [32768][512] = [K | V]
    float* biasT = (float*)(ws + 100663296);  //  2.10 MB  [h][q][k] * log2e
    bf16*  Wqg   = (bf16*)(ws + 102760448);   //  0.26 MB
    bf16*  Wkv   = (bf16*)(ws + 103022592);   //  0.26 MB
    bf16*  Wo    = (bf16*)(ws + 103284736);   //  0.13 MB
    float* b_gL  = (float*)(ws + 103415808);  //  1 KB

    prep_kernel<<<256, 256, 0, stream>>>(bias, w_q, w_k, w_v, w_g, w_o, b_g,
                                         biasT, Wqg, Wkv, Wo, b_gL);
    proj_kernel<<<4096, 256, 0, stream>>>(q, kv, Wqg, Wkv, QG, KV);
    attn_kernel<<<1024, 256, 0, stream>>>(QG, KV, biasT, mask, b_gL, OG);
    outproj_kernel<<<1024, 256, 0, stream>>>(OG, Wo, b_o, out);
}

// Round 12
// 213.543 us; speedup vs baseline: 1.0199x; 1.0188x over previous
//
#include <hip/hip_runtime.h>

typedef __bf16 bf16;
typedef __bf16 bf16x8 __attribute__((ext_vector_type(8)));
typedef __bf16 bf16x4 __attribute__((ext_vector_type(4)));
typedef float  f32x4  __attribute__((ext_vector_type(4)));
typedef unsigned int u32;
typedef unsigned int u32x2 __attribute__((ext_vector_type(2)));
typedef unsigned int u32x4 __attribute__((ext_vector_type(4)));
typedef unsigned short u16;

#define MFMA16(a, b, c) __builtin_amdgcn_mfma_f32_16x16x32_bf16((a), (b), (c), 0, 0, 0)
#define L2E 1.4426950408889634f

// B=1, S=128, R=256, C=256, H=8, Ca=32.  M = S*R = 32768, K = 256.

// ---- async global->LDS, 16 B per lane ----
typedef __attribute__((address_space(3))) u32 lds_u32;
typedef const __attribute__((address_space(1))) u32 glob_u32;
__device__ __forceinline__ void gll16(const void* g, void* l) {
    __builtin_amdgcn_global_load_lds((glob_u32*)g, (lds_u32*)l, 16, 0, 0);
}

__device__ __forceinline__ u32 pk2(float lo, float hi) {
    u16 a = __builtin_bit_cast(u16, (bf16)lo);
    u16 b = __builtin_bit_cast(u16, (bf16)hi);
    return ((u32)b << 16) | (u32)a;
}

__device__ __forceinline__ bf16x8 cvt8(float4 a, float4 b) {
    bf16x8 t;
    t[0]=(bf16)a.x; t[1]=(bf16)a.y; t[2]=(bf16)a.z; t[3]=(bf16)a.w;
    t[4]=(bf16)b.x; t[5]=(bf16)b.y; t[6]=(bf16)b.z; t[7]=(bf16)b.w;
    return t;
}

__device__ __forceinline__ float fexp2(float x) {
#if __has_builtin(__builtin_amdgcn_exp2f)
    return __builtin_amdgcn_exp2f(x);
#else
    return exp2f(x);
#endif
}
__device__ __forceinline__ float frcp(float x) {
#if __has_builtin(__builtin_amdgcn_rcpf)
    return __builtin_amdgcn_rcpf(x);
#else
    return 1.0f / x;
#endif
}

// ================= prep: ONLY Wqg/Wkv (proj's B inputs; ~0.5 MB L2-resident) ===
// biasT/Wo/b_gL moved to proj's grid tail (consumed only by attn/outproj; proj
// has ~3.7 TB/s of spare HBM BW to absorb their ~18 MB).
__global__ __launch_bounds__(256) void prep_kernel(
    const float* __restrict__ w_q, const float* __restrict__ w_k,
    const float* __restrict__ w_v, const float* __restrict__ w_g,
    bf16* __restrict__ Wqg, bf16* __restrict__ Wkv)
{
    const float norm = 0.17677669529663687f * L2E;   // 1/sqrt(32)*log2e (base-2 softmax)
    const int gid = blockIdx.x * 256 + threadIdx.x;
    const int gsz = gridDim.x * 256;

    for (int u = gid; u < 131072; u += gsz) {        // Wqg[n][k]
        int n = u >> 8, k = u & 255;
        float v = (n < 256) ? w_q[k * 256 + n] * norm : w_g[k * 256 + (n - 256)] * L2E;
        Wqg[u] = (bf16)v;
    }
    for (int u = gid; u < 131072; u += gsz) {        // Wkv[n][k]
        int n = u >> 8, k = u & 255;
        float v = (n < 256) ? w_k[k * 256 + n] : w_v[k * 256 + (n - 256)];
        Wkv[u] = (bf16)v;
    }
}

// ================= proj GEMM (round-9 core — best measured: 55.6us) ============
// 128x128 tile, BK=32, dbuf via 4 distinct __shared__ objects + unrolled steps
// (round-5: runtime LDS base defeats alias analysis).  gll16 bursts for B
// (round-7: per-lane strided streaming doubled time).  No As pad (round-10:
// pad fixed reads, conflicted staging writes).  64x128 retile refuted round-11:
// occupancy 34->53% with dur unchanged — proj is NOT wave-starved; 128-tile
// also keeps A-strip reuse inside the L2 window (FETCH 35 vs 81 MB).
__device__ __forceinline__ void proj_core(
    const float* __restrict__ A32, const bf16* __restrict__ Bw,
    bf16* __restrict__ Cb, int m0, int n0)
{
    __shared__ __align__(16) bf16 As0[128 * 32], Bs0[128 * 32];
    __shared__ __align__(16) bf16 As1[128 * 32], Bs1[128 * 32];

    const int tid  = threadIdx.x;
    const int lane = tid & 63, wave = tid >> 6;
    const int quad = lane >> 4, lc = lane & 15;
    const int wr = wave >> 1, wc = wave & 1;

    const int r0 = tid >> 2, p0 = tid & 3;
    const size_t offA0 = (size_t)(m0 + r0) * 256 + p0 * 8;
    const size_t offA1 = (size_t)(m0 + 64 + r0) * 256 + p0 * 8;
    const bf16* gB0 = Bw + (size_t)(n0 + r0) * 256 + p0 * 8;
    const bf16* gB1 = Bw + (size_t)(n0 + 64 + r0) * 256 + p0 * 8;

    f32x4 acc[4][4];
    #pragma unroll
    for (int i = 0; i < 4; ++i)
        #pragma unroll
        for (int j = 0; j < 4; ++j) acc[i][j] = f32x4{0.f, 0.f, 0.f, 0.f};

    {
        float4 x0 = *(const float4*)(A32 + offA0);
        float4 x1 = *(const float4*)(A32 + offA0 + 4);
        float4 y0 = *(const float4*)(A32 + offA1);
        float4 y1 = *(const float4*)(A32 + offA1 + 4);
        *(bf16x8*)(As0 + tid * 8)         = cvt8(x0, x1);
        *(bf16x8*)(As0 + (tid + 256) * 8) = cvt8(y0, y1);
        gll16(gB0, Bs0 + tid * 8);
        gll16(gB1, Bs0 + (tid + 256) * 8);
    }
    __syncthreads();

    auto step = [&](const bf16* Ac, const bf16* Bc, bf16* An, bf16* Bn,
                    int kn, bool pf) {
        float4 x0, x1, y0, y1;
        if (pf) {
            x0 = *(const float4*)(A32 + offA0 + kn);
            x1 = *(const float4*)(A32 + offA0 + kn + 4);
            y0 = *(const float4*)(A32 + offA1 + kn);
            y1 = *(const float4*)(A32 + offA1 + kn + 4);
            gll16(gB0 + kn, Bn + tid * 8);
            gll16(gB1 + kn, Bn + (tid + 256) * 8);
        }
        __builtin_amdgcn_sched_barrier(0);  // staging stays above, compute below

        bf16x8 aF[4], bF[4];
        #pragma unroll
        for (int mt = 0; mt < 4; ++mt)
            aF[mt] = *(const bf16x8*)(Ac + (wr * 64 + mt * 16 + lc) * 32 + quad * 8);
        #pragma unroll
        for (int nt = 0; nt < 4; ++nt)
            bF[nt] = *(const bf16x8*)(Bc + (wc * 64 + nt * 16 + lc) * 32 + quad * 8);
        #pragma unroll
        for (int mt = 0; mt < 4; ++mt)
            #pragma unroll
            for (int nt = 0; nt < 4; ++nt)
                acc[mt][nt] = MFMA16(aF[mt], bF[nt], acc[mt][nt]);

        if (pf) {
            *(bf16x8*)(An + tid * 8)         = cvt8(x0, x1);
            *(bf16x8*)(An + (tid + 256) * 8) = cvt8(y0, y1);
        }
        __syncthreads();
    };

    step(As0, Bs0, As1, Bs1,  32, true);
    step(As1, Bs1, As0, Bs0,  64, true);
    step(As0, Bs0, As1, Bs1,  96, true);
    step(As1, Bs1, As0, Bs0, 128, true);
    step(As0, Bs0, As1, Bs1, 160, true);
    step(As1, Bs1, As0, Bs0, 192, true);
    step(As0, Bs0, As1, Bs1, 224, true);
    step(As1, Bs1, As0, Bs0,   0, false);

    #pragma unroll
    for (int mt = 0; mt < 4; ++mt) {
        #pragma unroll
        for (int nt = 0; nt < 4; ++nt) {
            const int row = m0 + wr * 64 + mt * 16 + quad * 4;
            const int col = n0 + wc * 64 + nt * 16 + lc;
            #pragma unroll
            for (int rr = 0; rr < 4; ++rr)
                Cb[(size_t)(row + rr) * 512 + col] = (bf16)acc[mt][nt][rr];
        }
    }
}

// Grid 2112.  Blocks 0-2047: GEMM (round-9 strip remap: writer XCD = s%8,
// matching attn's reader — FETCH 68->35 MB win).  Blocks 2048-2111: prep tail
// (biasT coalesced-transpose + Wo + b_gL — no dependency on proj's output;
// rides proj's spare BW instead of serializing as a separate kernel).
__global__ __launch_bounds__(256) void proj_kernel(
    const float* __restrict__ qf, const float* __restrict__ kvf,
    const bf16* __restrict__ Wqg, const bf16* __restrict__ Wkv,
    bf16* __restrict__ QG, bf16* __restrict__ KV,
    const float* __restrict__ bias, const float* __restrict__ w_o,
    const float* __restrict__ b_g,
    float* __restrict__ biasT, bf16* __restrict__ Wo, float* __restrict__ b_gL)
{
    int bid = blockIdx.x;
    if (bid >= 2048) {
        const int gid = (bid - 2048) * 256 + threadIdx.x;   // 0..16383
        const int gsz = 64 * 256;
        // bias transpose, COALESCED: u = (q,k); read 8 consecutive floats (32 B
        // contiguous = the full h-vector), write 8 planes, each wave-contiguous.
        // (Old gather read 4 B per 64 B line -> ~8x over-fetch on a 16 MB input.)
        for (int u = gid; u < 65536; u += gsz) {
            float4 a = *(const float4*)(bias + (size_t)u * 8);
            float4 b = *(const float4*)(bias + (size_t)u * 8 + 4);
            biasT[          u] = a.x * L2E;
            biasT[ 65536 + u] = a.y * L2E;
            biasT[131072 + u] = a.z * L2E;
            biasT[196608 + u] = a.w * L2E;
            biasT[262144 + u] = b.x * L2E;
            biasT[327680 + u] = b.y * L2E;
            biasT[393216 + u] = b.z * L2E;
            biasT[458752 + u] = b.w * L2E;
        }
        for (int u = gid; u < 65536; u += gsz) {    // Wo[n][k] (w_o 0.26MB, L2-hot)
            int n = u >> 8, k = u & 255;
            Wo[u] = (bf16)w_o[k * 256 + n];
        }
        if (gid < 256) b_gL[gid] = b_g[gid] * L2E;
        return;
    }
    bool sel = bid >= 1024;
    int b = bid & 1023;
    int strip = ((b >> 3) & 1) | ((b & 7) << 1) | (((b >> 4) & 15) << 4);
    int m0 = strip * 128, n0 = (b >> 8) * 128;
    proj_core(sel ? kvf : qf, sel ? Wkv : Wqg, sel ? KV : QG, m0, n0);
}

// ============ outproj (round-9 version, unchanged) =============================
// 64x128 tile, grid 1024; reader strip mapped so XCD = s%8 -> OG (2.1 MB/XCD)
// is read from the writer XCD's L2.
__global__ __launch_bounds__(256) void outproj_kernel(
    const bf16* __restrict__ OG, const bf16* __restrict__ Wo,
    const float* __restrict__ bo, float* __restrict__ out)
{
    __shared__ __align__(16) bf16 As0[64 * 32], Bs0[128 * 32];
    __shared__ __align__(16) bf16 As1[64 * 32], Bs1[128 * 32];

    const int bid = blockIdx.x;
    const int x = bid & 7;
    const int strip = ((bid >> 3) & 3) | (x << 2) | (((bid >> 5) & 15) << 5);
    const int m0 = strip * 64, n0 = (bid >> 9) * 128;

    const int tid  = threadIdx.x;
    const int lane = tid & 63, wave = tid >> 6;
    const int quad = lane >> 4, lc = lane & 15;
    const int wr = wave >> 1, wc = wave & 1;   // wave tile: 32 x 64

    const int r0 = tid >> 2, p0 = tid & 3;
    const bf16* gA  = OG + (size_t)(m0 + r0) * 256 + p0 * 8;
    const bf16* gB0 = Wo + (size_t)(n0 + r0) * 256 + p0 * 8;
    const bf16* gB1 = Wo + (size_t)(n0 + 64 + r0) * 256 + p0 * 8;

    f32x4 acc[2][4];
    #pragma unroll
    for (int i = 0; i < 2; ++i)
        #pragma unroll
        for (int j = 0; j < 4; ++j) acc[i][j] = f32x4{0.f, 0.f, 0.f, 0.f};

    gll16(gA,  As0 + tid * 8);
    gll16(gB0, Bs0 + tid * 8);
    gll16(gB1, Bs0 + (tid + 256) * 8);
    __syncthreads();

    auto step = [&](const bf16* Ac, const bf16* Bc, bf16* An, bf16* Bn,
                    int kn, bool pf) {
        if (pf) {
            gll16(gA + kn,  An + tid * 8);
            gll16(gB0 + kn, Bn + tid * 8);
            gll16(gB1 + kn, Bn + (tid + 256) * 8);
        }
        __builtin_amdgcn_sched_barrier(0);

        bf16x8 aF[2], bF[4];
        #pragma unroll
        for (int mt = 0; mt < 2; ++mt)
            aF[mt] = *(const bf16x8*)(Ac + (wr * 32 + mt * 16 + lc) * 32 + quad * 8);
        #pragma unroll
        for (int nt = 0; nt < 4; ++nt)
            bF[nt] = *(const bf16x8*)(Bc + (wc * 64 + nt * 16 + lc) * 32 + quad * 8);
        #pragma unroll
        for (int mt = 0; mt < 2; ++mt)
            #pragma unroll
            for (int nt = 0; nt < 4; ++nt)
                acc[mt][nt] = MFMA16(aF[mt], bF[nt], acc[mt][nt]);
        __syncthreads();
    };

    step(As0, Bs0, As1, Bs1,  32, true);
    step(As1, Bs1, As0, Bs0,  64, true);
    step(As0, Bs0, As1, Bs1,  96, true);
    step(As1, Bs1, As0, Bs0, 128, true);
    step(As0, Bs0, As1, Bs1, 160, true);
    step(As1, Bs1, As0, Bs0, 192, true);
    step(As0, Bs0, As1, Bs1, 224, true);
    step(As1, Bs1, As0, Bs0,   0, false);

    #pragma unroll
    for (int mt = 0; mt < 2; ++mt) {
        #pragma unroll
        for (int nt = 0; nt < 4; ++nt) {
            const int row = m0 + wr * 32 + mt * 16 + quad * 4;
            const int col = n0 + wc * 64 + nt * 16 + lc;
            const float bb = bo[col];
            #pragma unroll
            for (int rr = 0; rr < 4; ++rr)
                out[(size_t)(row + rr) * 256 + col] = acc[mt][nt][rr] + bb;
        }
    }
}

// ================= attention per (s,h) — round-9 version (best: ~52us) =========
#define A_OFF_MASK 0
#define A_OFF_K    1024
#define A_OFF_VT   21504
#define A_LDS_TOT  (21504 + 32 * 264 * 2)   // 38400 B -> 4 blocks/CU

__global__ __launch_bounds__(256) void attn_kernel(
    const bf16* __restrict__ QG, const bf16* __restrict__ KV,
    const float* __restrict__ biasT, const float* __restrict__ bias_mask,
    const float* __restrict__ b_gL, bf16* __restrict__ OG)
{
    __shared__ __align__(16) char smem[A_LDS_TOT];
    float* maskadd = (float*)(smem + A_OFF_MASK);
    bf16*  Ks      = (bf16*)(smem + A_OFF_K);
    bf16*  Vt      = (bf16*)(smem + A_OFF_VT);

    const int tid  = threadIdx.x;
    const int wave = tid >> 6, lane = tid & 63;
    const int quad = lane >> 4, lc = lane & 15;
    const int h = blockIdx.x >> 7;       // all h of same s -> same XCD (bid%8 = s%8)
    const int s = blockIdx.x & 127;

    maskadd[tid] = (bias_mask[s * 256 + tid] - 1.0f) * (1e9f * L2E);
    {
        const bf16* kvrow = KV + (size_t)(s * 256 + tid) * 512 + h * 32;
        #pragma unroll
        for (int j = 0; j < 4; ++j)
            *(bf16x8*)(Ks + tid * 40 + j * 8) = *(const bf16x8*)(kvrow + j * 8);
        bf16x8 vx[4];
        #pragma unroll
        for (int j = 0; j < 4; ++j) vx[j] = *(const bf16x8*)(kvrow + 256 + j * 8);
        #pragma unroll
        for (int d = 0; d < 32; ++d)
            Vt[d * 264 + tid] = vx[d >> 3][d & 7];
    }
    __syncthreads();

    const f32x4 bg0 = *(const f32x4*)(b_gL + h * 32 + quad * 4);
    const f32x4 bg1 = *(const f32x4*)(b_gL + h * 32 + 16 + quad * 4);

    #pragma unroll 1
    for (int p = 0; p < 4; ++p) {
        const int q0 = (wave * 4 + p) * 16;

        bf16x8 qf = *(const bf16x8*)(QG + (size_t)(s * 256 + q0 + lc) * 512 + h * 32 + quad * 8);

        const float* bT = biasT + (((size_t)h * 256 + q0 + lc) << 8) + quad * 4;
        u32x2 cw[16];
        float sum = 0.f;
        #pragma unroll
        for (int half = 0; half < 2; ++half) {
            f32x4 sc[8];
            #pragma unroll
            for (int k8 = 0; k8 < 8; ++k8) {
                const int kt = half * 8 + k8;
                bf16x8 kf = *(const bf16x8*)(Ks + (kt * 16 + lc) * 40 + quad * 8);
                f32x4 z = {0.f, 0.f, 0.f, 0.f};
                sc[k8] = MFMA16(kf, qf, z);
            }
            #pragma unroll
            for (int k8 = 0; k8 < 8; ++k8) {
                const int kt = half * 8 + k8;
                f32x4 bv = *(const f32x4*)(bT + kt * 16);
                f32x4 mv = *(const f32x4*)(maskadd + kt * 16 + quad * 4);
                f32x4 t = sc[k8] + bv + mv;
                float e0 = fexp2(t[0]);
                float e1 = fexp2(t[1]);
                float e2 = fexp2(t[2]);
                float e3 = fexp2(t[3]);
                sum += (e0 + e1) + (e2 + e3);
                cw[kt] = u32x2{pk2(e0, e1), pk2(e2, e3)};
            }
            __builtin_amdgcn_sched_barrier(0x6);
        }

        const bf16* gp = QG + (size_t)(s * 256 + q0 + lc) * 512 + 256 + h * 32 + quad * 4;
        bf16x4 gv0 = *(const bf16x4*)(gp);
        bf16x4 gv1 = *(const bf16x4*)(gp + 16);

        f32x4 o0 = {0.f, 0.f, 0.f, 0.f}, o1 = {0.f, 0.f, 0.f, 0.f};
        #pragma unroll
        for (int ks = 0; ks < 8; ++ks) {
            u32 c0 = cw[2 * ks].x,     c1 = cw[2 * ks].y;
            u32 c2 = cw[2 * ks + 1].x, c3 = cw[2 * ks + 1].y;
            u32x2 s02 = __builtin_amdgcn_permlane32_swap(c0, c2, false, false);
            u32x2 s13 = __builtin_amdgcn_permlane32_swap(c1, c3, false, false);
            u32x2 e02 = __builtin_amdgcn_permlane16_swap(s02.x, s02.y, false, false);
            u32x2 e13 = __builtin_amdgcn_permlane16_swap(s13.x, s13.y, false, false);
            u32x4 pw = {e02.x, e13.x, e02.y, e13.y};
            bf16x8 pf = __builtin_bit_cast(bf16x8, pw);
            bf16x8 v0 = *(const bf16x8*)(Vt + lc * 264 + ks * 32 + quad * 8);
            bf16x8 v1 = *(const bf16x8*)(Vt + (16 + lc) * 264 + ks * 32 + quad * 8);
            o0 = MFMA16(v0, pf, o0);
            o1 = MFMA16(v1, pf, o1);
        }

        sum += __shfl_xor(sum, 16, 64);
        sum += __shfl_xor(sum, 32, 64);
        const float inv = frcp(sum);

        bf16* op = OG + (size_t)(s * 256 + q0 + lc) * 256 + h * 32 + quad * 4;
        #pragma unroll
        for (int nt = 0; nt < 2; ++nt) {
            f32x4 ov = nt ? o1 : o0;
            f32x4 bg = nt ? bg1 : bg0;
            bf16x4 gv = nt ? gv1 : gv0;
            bf16x4 ob;
            #pragma unroll
            for (int rr = 0; rr < 4; ++rr) {
                float e = fexp2(-((float)gv[rr] + bg[rr]));
                float g = frcp(1.0f + e);
                ob[rr] = (bf16)(ov[rr] * (inv * g));
            }
            *(bf16x4*)(op + nt * 16) = ob;
        }
    }
}

// ================= launch =================
extern "C" void kernel_launch(void* const* d_in, const int* in_sizes, int n_in,
                              void* d_out, int out_size, void* d_ws, size_t ws_size,
                              hipStream_t stream)
{
    (void)in_sizes; (void)n_in; (void)out_size; (void)ws_size;
    const float* q    = (const float*)d_in[0];
    const float* kv   = (const float*)d_in[1];
    const float* bias = (const float*)d_in[2];
    const float* mask = (const float*)d_in[3];
    const float* w_q  = (const float*)d_in[4];
    const float* w_k  = (const float*)d_in[5];
    const float* w_v  = (const float*)d_in[6];
    const float* w_g  = (const float*)d_in[7];
    const float* b_g  = (const float*)d_in[8];
    const float* w_o  = (const float*)d_in[9];
    const float* b_o  = (const float*)d_in[10];
    float* out = (float*)d_out;

    char* ws = (char*)d_ws;
    bf16*  OG    = (bf16*)(ws + 0);           // 16.78 MB  [M][256]
    bf16*  QG    = (bf16*)(ws + 33554432);    // 33.55 MB  [32768][512] = [Q*norm | G*l2e]
    bf16*  KV    = (bf16*)(ws + 67108864);    // 33.55 MB  [32768][512] = [K | V]
    float* biasT = (float*)(ws + 100663296);  //  2.10 MB  [h][q][k] * log2e
    bf16*  Wqg   = (bf16*)(ws + 102760448);   //  0.26 MB
    bf16*  Wkv   = (bf16*)(ws + 103022592);   //  0.26 MB
    bf16*  Wo    = (bf16*)(ws + 103284736);   //  0.13 MB
    float* b_gL  = (float*)(ws + 103415808);  //  1 KB

    prep_kernel<<<64, 256, 0, stream>>>(w_q, w_k, w_v, w_g, Wqg, Wkv);
    proj_kernel<<<2112, 256, 0, stream>>>(q, kv, Wqg, Wkv, QG, KV,
                                          bias, w_o, b_g, biasT, Wo, b_gL);
    attn_kernel<<<1024, 256, 0, stream>>>(QG, KV, biasT, mask, b_gL, OG);
    outproj_kernel<<<1024, 256, 0, stream>>>(OG, Wo, b_o, out);
}